// Round 6
// baseline (141.917 us; speedup 1.0000x reference)
//
#include <hip/hip_runtime.h>
#include <hip/hip_cooperative_groups.h>
#include <math.h>

namespace cg = cooperative_groups;

#define NPROP 2000
#define NCLS  81
#define NFG   80
#define NDET  100
#define NBLK  512
#define VMAX  512
#define WMAX  16          // VMAX/32 words per suppression-matrix row
#define SLICE 25          // proposals per block in phase A (80*25 = 2000)

#define IMGW 800.0f
#define IMGH 800.0f
#define SCORE_THRESH 0.05f
#define NMS_THRESH 0.5f
#define MIN_SIZE 1.0f
#define BBOX_CLIP 4.135166556742356f  // log(1000/16)

// ONE cooperative kernel: phase A (distributed transpose + bitwise-exact scores),
// grid sync, phase B (per-class sort + bitmask NMS + output).
__global__ __launch_bounds__(NBLK) void fused_kernel(
        const float* __restrict__ logits,  // [NPROP, NCLS]
        const float* __restrict__ reg,     // [NPROP, NCLS*4]
        const float* __restrict__ prop,    // [NPROP, 4]
        float* __restrict__ scoreT,        // ws: [NFG, NPROP]
        float* __restrict__ regT,          // ws: [NFG, NPROP, 4]
        float* __restrict__ out) {
    const int tid  = threadIdx.x;
    const int lane = tid & 63;
    const int wv   = tid >> 6;

    // ---- phase A shared ----
    __shared__ float tileL[SLICE * NCLS];      // 8.1 KB
    __shared__ float tileR[SLICE * NCLS * 4];  // 32.4 KB
    __shared__ float s_m[SLICE], s_s[SLICE];
    // ---- phase B shared ----
    __shared__ float s_x1u[NPROP], s_y1u[NPROP], s_x2u[NPROP], s_y2u[NPROP];
    __shared__ float s_scu[NPROP];
    __shared__ float s_vsc[NPROP];
    __shared__ unsigned short s_vlist[NPROP];
    __shared__ unsigned short s_ord[NPROP];
    __shared__ unsigned char  s_keep[NPROP];
    __shared__ unsigned int   s_supm[VMAX * WMAX];   // 32.8 KB
    __shared__ unsigned short s_keepOut[NDET], s_supOut[NDET], s_invOut[NDET];
    __shared__ int s_cnt, s_K, s_wcnt[8];

    // ================= phase A: my 25-proposal slice =================
    {
        const int n0 = blockIdx.x * SLICE;
        for (int t = tid; t < SLICE * NCLS; t += NBLK)
            tileL[t] = logits[n0 * NCLS + t];
        __syncthreads();
        if (tid < SLICE) {
            const float* row = tileL + tid * NCLS;
            float m = -1e30f;
            for (int k = 0; k < NCLS; ++k) m = fmaxf(m, row[k]);
            float s = 0.0f;
            for (int k = 0; k < NCLS; ++k) s += expf(row[k] - m);
            s_m[tid] = m;
            s_s[tid] = s;
        }
        __syncthreads();
        for (int t = tid; t < NFG * SLICE; t += NBLK) {
            int cc = t / SLICE, i = t - cc * SLICE;
            scoreT[cc * NPROP + n0 + i] =
                expf(tileL[i * NCLS + (cc + 1)] - s_m[i]) / s_s[i];
        }
        for (int t = tid; t < SLICE * NCLS * 4; t += NBLK)
            tileR[t] = reg[(size_t)n0 * (NCLS * 4) + t];
        __syncthreads();
        for (int t = tid; t < NFG * SLICE; t += NBLK) {
            int cc = t / SLICE, i = t - cc * SLICE;
            const float* src = tileR + i * (NCLS * 4) + (cc + 1) * 4;
            ((float4*)regT)[cc * NPROP + n0 + i] =
                make_float4(src[0], src[1], src[2], src[3]);
        }
    }
    __threadfence();                 // device-scope visibility across XCDs
    cg::this_grid().sync();

    // ================= phase B: per-class pipeline =================
    const int cc = blockIdx.x;       // class = cc+1

    if (tid == 0) s_cnt = 0;
    __syncthreads();

    // ---- decode + clip + validity (all loads coalesced) ----
    for (int n = tid; n < NPROP; n += NBLK) {
        float sc = scoreT[cc * NPROP + n];

        float4 pr = ((const float4*)prop)[n];
        float w  = pr.z - pr.x, h = pr.w - pr.y;
        float cx = pr.x + 0.5f * w, cy = pr.y + 0.5f * h;
        float4 d = ((const float4*)regT)[cc * NPROP + n];
        float dx = d.x / 10.0f;
        float dy = d.y / 10.0f;
        float dw = fminf(d.z / 5.0f, BBOX_CLIP);
        float dh = fminf(d.w / 5.0f, BBOX_CLIP);
        float pcx = dx * w + cx;
        float pcy = dy * h + cy;
        float pw  = expf(dw) * w;
        float ph  = expf(dh) * h;
        float bx1 = fminf(fmaxf(pcx - 0.5f * pw, 0.0f), IMGW);
        float by1 = fminf(fmaxf(pcy - 0.5f * ph, 0.0f), IMGH);
        float bx2 = fminf(fmaxf(pcx + 0.5f * pw, 0.0f), IMGW);
        float by2 = fminf(fmaxf(pcy + 0.5f * ph, 0.0f), IMGH);
        s_x1u[n] = bx1; s_y1u[n] = by1; s_x2u[n] = bx2; s_y2u[n] = by2;
        bool valid = (sc >= SCORE_THRESH) && ((bx2 - bx1) >= MIN_SIZE)
                                          && ((by2 - by1) >= MIN_SIZE);
        s_scu[n] = valid ? sc : -1.0f;
        if (valid) {
            int p = atomicAdd(&s_cnt, 1);
            s_vlist[p] = (unsigned short)n;
            s_vsc[p]   = sc;
        }
    }
    __syncthreads();
    const int V = s_cnt;

    // ---- rank sort (score desc, index asc) ----
    for (int i = tid; i < V; i += NBLK) {
        float si = s_vsc[i];
        int   ni = s_vlist[i];
        int r = 0;
        for (int j = 0; j < V; ++j) {
            float sj = s_vsc[j];
            int   nj = s_vlist[j];
            r += (sj > si) || (sj == si && nj < ni);
        }
        s_ord[r] = (unsigned short)ni;
    }
    __syncthreads();

    int K;

    if (V <= VMAX) {
        // ---- suppression bit matrix ----
        const int W = (V + 31) >> 5;
        for (int t = tid; t < V * W; t += NBLK) {
            int i = t / W, w = t - i * W;
            int ni = s_ord[i];
            float ax1 = s_x1u[ni], ay1 = s_y1u[ni], ax2 = s_x2u[ni], ay2 = s_y2u[ni];
            float areaA = (ax2 - ax1) * (ay2 - ay1);
            unsigned int bits = 0;
            int jbase = w << 5;
            int jend  = (jbase + 32 < V) ? jbase + 32 : V;
            int j0    = (jbase > i + 1) ? jbase : i + 1;
            for (int j = j0; j < jend; ++j) {
                int nj = s_ord[j];
                float bx1 = s_x1u[nj], by1 = s_y1u[nj], bx2 = s_x2u[nj], by2 = s_y2u[nj];
                float areaB = (bx2 - bx1) * (by2 - by1);
                float lx = fmaxf(ax1, bx1), ly = fmaxf(ay1, by1);
                float rx = fminf(ax2, bx2), ry = fminf(ay2, by2);
                float iw = fmaxf(rx - lx, 0.0f), ih = fmaxf(ry - ly, 0.0f);
                float inter = iw * ih;
                float iou = inter / (areaA + areaB - inter + 1e-9f);
                if (iou > NMS_THRESH) bits |= 1u << (j - jbase);
            }
            s_supm[i * W + w] = bits;
        }
        __syncthreads();

        // ---- serial greedy scan, single wave, register keep-mask ----
        unsigned int kw = 0;
        if (wv == 0) {
            int base = lane << 5;
            if (base < V) kw = (V - base >= 32) ? 0xffffffffu
                                                : ((1u << (V - base)) - 1u);
            int nk = 0;
            unsigned int nrow = (V > 0 && lane < W) ? s_supm[lane] : 0u;
            for (int i = 0; i < V; ++i) {
                unsigned int rowb = nrow;
                if (i + 1 < V) nrow = (lane < W) ? s_supm[(i + 1) * W + lane] : 0u;
                unsigned int kword = (unsigned int)__shfl((int)kw, i >> 5);
                if ((kword >> (i & 31)) & 1u) {
                    if (lane == 0) s_keepOut[nk] = (unsigned short)i;
                    ++nk;
                    if (nk == NDET) break;
                    kw &= ~rowb;
                }
            }
            if (lane == 0) s_K = nk;
        }
        __syncthreads();
        K = s_K;

        // ---- wave-local compactions ----
        if (K < NDET) {
            if (wv == 0) {
                int b = 0;
                for (int start = 0; start < V && b < NDET; start += 64) {
                    int p = start + lane;
                    unsigned int kword = (unsigned int)__shfl((int)kw, (p >> 5) & 15);
                    bool f = (p < V) && !((kword >> (p & 31)) & 1u);
                    unsigned long long mb = __ballot(f);
                    int pos = b + __popcll(mb & ((1ull << lane) - 1ull));
                    if (f && pos < NDET) s_supOut[pos] = (unsigned short)p;
                    b += (int)__popcll(mb);
                }
            } else if (wv == 1) {
                int b = 0;
                for (int start = 0; start < NPROP && b < NDET; start += 64) {
                    int n = start + lane;
                    bool f = (s_scu[n] < 0.0f);
                    unsigned long long mb = __ballot(f);
                    int pos = b + __popcll(mb & ((1ull << lane) - 1ull));
                    if (f && pos < NDET) s_invOut[pos] = (unsigned short)n;
                    b += (int)__popcll(mb);
                }
            }
        }
        __syncthreads();
    } else {
        // ---- fallback (V > VMAX): block-wide greedy NMS ----
        for (int p = tid; p < V; p += NBLK) s_keep[p] = 1;
        __syncthreads();
        int nk = 0;
        for (int i = 0; i < V; ++i) {
            if (s_keep[i]) {
                if (tid == 0) s_keepOut[nk] = (unsigned short)i;
                nk++;
                if (nk == NDET) break;
                int ni = s_ord[i];
                float ax1 = s_x1u[ni], ay1 = s_y1u[ni], ax2 = s_x2u[ni], ay2 = s_y2u[ni];
                float areaA = (ax2 - ax1) * (ay2 - ay1);
                for (int j = i + 1 + tid; j < V; j += NBLK) {
                    if (!s_keep[j]) continue;
                    int nj = s_ord[j];
                    float bx1 = s_x1u[nj], by1 = s_y1u[nj], bx2 = s_x2u[nj], by2 = s_y2u[nj];
                    float areaB = (bx2 - bx1) * (by2 - by1);
                    float lx = fmaxf(ax1, bx1), ly = fmaxf(ay1, by1);
                    float rx = fminf(ax2, bx2), ry = fminf(ay2, by2);
                    float iw = fmaxf(rx - lx, 0.0f), ih = fmaxf(ry - ly, 0.0f);
                    float inter = iw * ih;
                    float iou = inter / (areaA + areaB - inter + 1e-9f);
                    if (iou > NMS_THRESH) s_keep[j] = 0;
                }
                __syncthreads();
            }
        }
        if (tid == 0) s_K = nk;
        __syncthreads();
        K = s_K;

        if (K < NDET) {
            int base = 0;
            for (int start = 0; start < V && base < NDET; start += NBLK) {
                int p = start + tid;
                bool f = (p < V) && (!s_keep[p]);
                unsigned long long mb = __ballot(f);
                if (lane == 0) s_wcnt[wv] = __popcll(mb);
                __syncthreads();
                int wbase = base;
                for (int ww = 0; ww < wv; ++ww) wbase += s_wcnt[ww];
                if (f) {
                    int pos = wbase + __popcll(mb & ((1ull << lane) - 1ull));
                    if (pos < NDET) s_supOut[pos] = (unsigned short)p;
                }
                for (int ww = 0; ww < 8; ++ww) base += s_wcnt[ww];
                __syncthreads();
            }
            base = 0;
            for (int start = 0; start < NPROP && base < NDET; start += NBLK) {
                int n = start + tid;
                bool f = (n < NPROP) && (s_scu[n] < 0.0f);
                unsigned long long mb = __ballot(f);
                if (lane == 0) s_wcnt[wv] = __popcll(mb);
                __syncthreads();
                int wbase = base;
                for (int ww = 0; ww < wv; ++ww) wbase += s_wcnt[ww];
                if (f) {
                    int pos = wbase + __popcll(mb & ((1ull << lane) - 1ull));
                    if (pos < NDET) s_invOut[pos] = (unsigned short)n;
                }
                for (int ww = 0; ww < 8; ++ww) base += s_wcnt[ww];
                __syncthreads();
            }
        }
        __syncthreads();
    }

    const int nsupT = (K < NDET) ? (V - K) : 0;

    // ---- output: boxes | scores | labels | valid (class-major) ----
    float* out_boxes  = out;
    float* out_scores = out + NFG * NDET * 4;
    float* out_labels = out + NFG * NDET * 4 + NFG * NDET;
    float* out_valid  = out + NFG * NDET * 4 + 2 * NFG * NDET;
    const int base_o = cc * NDET;

    for (int k = tid; k < NDET; k += NBLK) {
        int n; float sc, vf;
        if (k < K) {
            n = s_ord[s_keepOut[k]];
            sc = s_scu[n]; vf = 1.0f;
        } else {
            int j = k - K;
            n = (j < nsupT) ? s_ord[s_supOut[j]] : s_invOut[j - nsupT];
            sc = -1.0f; vf = 0.0f;
        }
        out_boxes[(base_o + k) * 4 + 0] = s_x1u[n];
        out_boxes[(base_o + k) * 4 + 1] = s_y1u[n];
        out_boxes[(base_o + k) * 4 + 2] = s_x2u[n];
        out_boxes[(base_o + k) * 4 + 3] = s_y2u[n];
        out_scores[base_o + k] = sc;
        out_labels[base_o + k] = (float)(cc + 1);
        out_valid[base_o + k]  = vf;
    }
}

extern "C" void kernel_launch(void* const* d_in, const int* in_sizes, int n_in,
                              void* d_out, int out_size, void* d_ws, size_t ws_size,
                              hipStream_t stream) {
    const float* logits = (const float*)d_in[0];  // [2000, 81]
    const float* reg    = (const float*)d_in[1];  // [2000, 324]
    const float* prop   = (const float*)d_in[2];  // [2000, 4]
    float* out    = (float*)d_out;
    float* scoreT = (float*)d_ws;                  // 80*2000 floats
    float* regT   = scoreT + NFG * NPROP;          // 80*2000*4 floats

    void* args[] = { (void*)&logits, (void*)&reg, (void*)&prop,
                     (void*)&scoreT, (void*)&regT, (void*)&out };
    hipLaunchCooperativeKernel((const void*)fused_kernel,
                               dim3(NFG), dim3(NBLK), args, 0, stream);
}

// Round 7
// 101.179 us; speedup vs baseline: 1.4026x; 1.4026x over previous
//
#include <hip/hip_runtime.h>
#include <math.h>

#define NPROP 2000
#define NCLS  81
#define NFG   80
#define NDET  100
#define NBLK  512
#define VMAX  512
#define WMAX  16          // VMAX/32 words per suppression-matrix row

#define R     8           // rows per prep block; grid = 2000/8 = 250
#define PBLK  256

#define IMGW 800.0f
#define IMGH 800.0f
#define SCORE_THRESH 0.05f
#define NMS_THRESH 0.5f
#define MIN_SIZE 1.0f
#define BBOX_CLIP 4.135166556742356f  // log(1000/16)

// ---------------- kernel 1: prep — per-(n,class) score + decoded/clipped box ----------------
// scoreV[cc][n] = valid ? softmax_score : -1    (bitwise-identical op order)
// boxT  [cc][n] = clipped decoded box (float4)  (identical decode expression)
__global__ __launch_bounds__(PBLK) void prep_kernel(const float* __restrict__ logits,
                                                    const float* __restrict__ reg,
                                                    const float* __restrict__ prop,
                                                    float* __restrict__ scoreV,
                                                    float4* __restrict__ boxT) {
    __shared__ float  tl[R * NCLS];        // 8*81*4   = 2.6 KB
    __shared__ float  tr[R * NCLS * 4];    // 8*324*4  = 10.4 KB
    __shared__ float4 tp[R];
    __shared__ float  sm[R], ss[R];
    const int n0 = blockIdx.x * R;

    // stage logits rows (coalesced)
    for (int t = threadIdx.x; t < R * NCLS; t += PBLK)
        tl[t] = logits[n0 * NCLS + t];
    // stage reg rows as float4 (row stride 324 floats = 81 float4, 16B-aligned)
    for (int t = threadIdx.x; t < R * NCLS; t += PBLK)
        ((float4*)tr)[t] = ((const float4*)reg)[(size_t)n0 * NCLS + t];
    if (threadIdx.x < R)
        tp[threadIdx.x] = ((const float4*)prop)[n0 + threadIdx.x];
    __syncthreads();

    // per-row stats: SAME sequential fmaxf / expf-sum chain (bitwise-validated)
    if (threadIdx.x < R) {
        const float* row = tl + threadIdx.x * NCLS;
        float m = -1e30f;
        for (int k = 0; k < NCLS; ++k) m = fmaxf(m, row[k]);
        float s = 0.0f;
        for (int k = 0; k < NCLS; ++k) s += expf(row[k] - m);
        sm[threadIdx.x] = m;
        ss[threadIdx.x] = s;
    }
    __syncthreads();

    // 640 (cc,i) items: score + decode + clip + validity
    for (int t = threadIdx.x; t < NFG * R; t += PBLK) {
        int cc = t >> 3, i = t & 7;              // cc-major -> packed writes
        int c  = cc + 1;
        float sc = expf(tl[i * NCLS + c] - sm[i]) / ss[i];

        float4 pr = tp[i];
        float w  = pr.z - pr.x, h = pr.w - pr.y;
        float cx = pr.x + 0.5f * w, cy = pr.y + 0.5f * h;
        const float* d = tr + i * (NCLS * 4) + c * 4;
        float dx = d[0] / 10.0f;
        float dy = d[1] / 10.0f;
        float dw = fminf(d[2] / 5.0f, BBOX_CLIP);
        float dh = fminf(d[3] / 5.0f, BBOX_CLIP);
        float pcx = dx * w + cx;
        float pcy = dy * h + cy;
        float pw  = expf(dw) * w;
        float ph  = expf(dh) * h;
        float bx1 = fminf(fmaxf(pcx - 0.5f * pw, 0.0f), IMGW);
        float by1 = fminf(fmaxf(pcy - 0.5f * ph, 0.0f), IMGH);
        float bx2 = fminf(fmaxf(pcx + 0.5f * pw, 0.0f), IMGW);
        float by2 = fminf(fmaxf(pcy + 0.5f * ph, 0.0f), IMGH);
        bool valid = (sc >= SCORE_THRESH) && ((bx2 - bx1) >= MIN_SIZE)
                                          && ((by2 - by1) >= MIN_SIZE);
        int n = n0 + i;
        scoreV[cc * NPROP + n] = valid ? sc : -1.0f;
        boxT[cc * NPROP + n]   = make_float4(bx1, by1, bx2, by2);
    }
}

// ---------------- kernel 2: one block per foreground class ----------------
__global__ __launch_bounds__(NBLK) void perclass_kernel(
        const float* __restrict__ scoreV,  // [NFG, NPROP]
        const float4* __restrict__ boxT,   // [NFG, NPROP]
        float* __restrict__ out) {
    const int cc   = blockIdx.x;       // class = cc+1
    const int tid  = threadIdx.x;
    const int lane = tid & 63;
    const int wv   = tid >> 6;

    __shared__ float s_x1u[NPROP], s_y1u[NPROP], s_x2u[NPROP], s_y2u[NPROP];
    __shared__ float s_scu[NPROP];                 // score if valid else -1
    __shared__ float s_vsc[NPROP];
    __shared__ unsigned short s_vlist[NPROP];
    __shared__ unsigned short s_ord[NPROP];
    __shared__ unsigned char  s_keep[NPROP];
    __shared__ unsigned int   s_supm[VMAX * WMAX];
    __shared__ unsigned short s_keepOut[NDET], s_supOut[NDET], s_invOut[NDET];
    __shared__ int s_cnt, s_K, s_wcnt[8];

    if (tid == 0) s_cnt = 0;
    __syncthreads();

    // ---- phase 1: pure load (no arithmetic) + valid-list build ----
    for (int n = tid; n < NPROP; n += NBLK) {
        float  sc = scoreV[cc * NPROP + n];
        float4 b  = boxT[cc * NPROP + n];
        s_x1u[n] = b.x; s_y1u[n] = b.y; s_x2u[n] = b.z; s_y2u[n] = b.w;
        s_scu[n] = sc;
        if (sc >= 0.0f) {
            int p = atomicAdd(&s_cnt, 1);
            s_vlist[p] = (unsigned short)n;
            s_vsc[p]   = sc;
        }
    }
    __syncthreads();
    const int V = s_cnt;

    // ---- phase 2: rank sort (score desc, index asc) ----
    for (int i = tid; i < V; i += NBLK) {
        float si = s_vsc[i];
        int   ni = s_vlist[i];
        int r = 0;
        for (int j = 0; j < V; ++j) {
            float sj = s_vsc[j];
            int   nj = s_vlist[j];
            r += (sj > si) || (sj == si && nj < ni);
        }
        s_ord[r] = (unsigned short)ni;
    }
    __syncthreads();

    int K;

    if (V <= VMAX) {
        // ---- suppression bit matrix ----
        const int W = (V + 31) >> 5;
        for (int t = tid; t < V * W; t += NBLK) {
            int i = t / W, w = t - i * W;
            int ni = s_ord[i];
            float ax1 = s_x1u[ni], ay1 = s_y1u[ni], ax2 = s_x2u[ni], ay2 = s_y2u[ni];
            float areaA = (ax2 - ax1) * (ay2 - ay1);
            unsigned int bits = 0;
            int jbase = w << 5;
            int jend  = (jbase + 32 < V) ? jbase + 32 : V;
            int j0    = (jbase > i + 1) ? jbase : i + 1;
            for (int j = j0; j < jend; ++j) {
                int nj = s_ord[j];
                float bx1 = s_x1u[nj], by1 = s_y1u[nj], bx2 = s_x2u[nj], by2 = s_y2u[nj];
                float areaB = (bx2 - bx1) * (by2 - by1);
                float lx = fmaxf(ax1, bx1), ly = fmaxf(ay1, by1);
                float rx = fminf(ax2, bx2), ry = fminf(ay2, by2);
                float iw = fmaxf(rx - lx, 0.0f), ih = fmaxf(ry - ly, 0.0f);
                float inter = iw * ih;
                float iou = inter / (areaA + areaB - inter + 1e-9f);
                if (iou > NMS_THRESH) bits |= 1u << (j - jbase);
            }
            s_supm[i * W + w] = bits;
        }
        __syncthreads();

        // ---- serial greedy scan, single wave, register keep-mask ----
        unsigned int kw = 0;
        if (wv == 0) {
            int base = lane << 5;
            if (base < V) kw = (V - base >= 32) ? 0xffffffffu
                                                : ((1u << (V - base)) - 1u);
            int nk = 0;
            unsigned int nrow = (V > 0 && lane < W) ? s_supm[lane] : 0u;
            for (int i = 0; i < V; ++i) {
                unsigned int rowb = nrow;
                if (i + 1 < V) nrow = (lane < W) ? s_supm[(i + 1) * W + lane] : 0u;
                unsigned int kword = (unsigned int)__shfl((int)kw, i >> 5);
                if ((kword >> (i & 31)) & 1u) {
                    if (lane == 0) s_keepOut[nk] = (unsigned short)i;
                    ++nk;
                    if (nk == NDET) break;
                    kw &= ~rowb;
                }
            }
            if (lane == 0) s_K = nk;
        }
        __syncthreads();
        K = s_K;

        // ---- wave-local compactions ----
        if (K < NDET) {
            if (wv == 0) {
                int b = 0;
                for (int start = 0; start < V && b < NDET; start += 64) {
                    int p = start + lane;
                    unsigned int kword = (unsigned int)__shfl((int)kw, (p >> 5) & 15);
                    bool f = (p < V) && !((kword >> (p & 31)) & 1u);
                    unsigned long long mb = __ballot(f);
                    int pos = b + __popcll(mb & ((1ull << lane) - 1ull));
                    if (f && pos < NDET) s_supOut[pos] = (unsigned short)p;
                    b += (int)__popcll(mb);
                }
            } else if (wv == 1) {
                int b = 0;
                for (int start = 0; start < NPROP && b < NDET; start += 64) {
                    int n = start + lane;
                    bool f = (s_scu[n] < 0.0f);
                    unsigned long long mb = __ballot(f);
                    int pos = b + __popcll(mb & ((1ull << lane) - 1ull));
                    if (f && pos < NDET) s_invOut[pos] = (unsigned short)n;
                    b += (int)__popcll(mb);
                }
            }
        }
        __syncthreads();
    } else {
        // ---- fallback (V > VMAX): block-wide greedy NMS ----
        for (int p = tid; p < V; p += NBLK) s_keep[p] = 1;
        __syncthreads();
        int nk = 0;
        for (int i = 0; i < V; ++i) {
            if (s_keep[i]) {
                if (tid == 0) s_keepOut[nk] = (unsigned short)i;
                nk++;
                if (nk == NDET) break;
                int ni = s_ord[i];
                float ax1 = s_x1u[ni], ay1 = s_y1u[ni], ax2 = s_x2u[ni], ay2 = s_y2u[ni];
                float areaA = (ax2 - ax1) * (ay2 - ay1);
                for (int j = i + 1 + tid; j < V; j += NBLK) {
                    if (!s_keep[j]) continue;
                    int nj = s_ord[j];
                    float bx1 = s_x1u[nj], by1 = s_y1u[nj], bx2 = s_x2u[nj], by2 = s_y2u[nj];
                    float areaB = (bx2 - bx1) * (by2 - by1);
                    float lx = fmaxf(ax1, bx1), ly = fmaxf(ay1, by1);
                    float rx = fminf(ax2, bx2), ry = fminf(ay2, by2);
                    float iw = fmaxf(rx - lx, 0.0f), ih = fmaxf(ry - ly, 0.0f);
                    float inter = iw * ih;
                    float iou = inter / (areaA + areaB - inter + 1e-9f);
                    if (iou > NMS_THRESH) s_keep[j] = 0;
                }
                __syncthreads();
            }
        }
        if (tid == 0) s_K = nk;
        __syncthreads();
        K = s_K;

        if (K < NDET) {
            int base = 0;
            for (int start = 0; start < V && base < NDET; start += NBLK) {
                int p = start + tid;
                bool f = (p < V) && (!s_keep[p]);
                unsigned long long mb = __ballot(f);
                if (lane == 0) s_wcnt[wv] = __popcll(mb);
                __syncthreads();
                int wbase = base;
                for (int ww = 0; ww < wv; ++ww) wbase += s_wcnt[ww];
                if (f) {
                    int pos = wbase + __popcll(mb & ((1ull << lane) - 1ull));
                    if (pos < NDET) s_supOut[pos] = (unsigned short)p;
                }
                for (int ww = 0; ww < 8; ++ww) base += s_wcnt[ww];
                __syncthreads();
            }
            base = 0;
            for (int start = 0; start < NPROP && base < NDET; start += NBLK) {
                int n = start + tid;
                bool f = (n < NPROP) && (s_scu[n] < 0.0f);
                unsigned long long mb = __ballot(f);
                if (lane == 0) s_wcnt[wv] = __popcll(mb);
                __syncthreads();
                int wbase = base;
                for (int ww = 0; ww < wv; ++ww) wbase += s_wcnt[ww];
                if (f) {
                    int pos = wbase + __popcll(mb & ((1ull << lane) - 1ull));
                    if (pos < NDET) s_invOut[pos] = (unsigned short)n;
                }
                for (int ww = 0; ww < 8; ++ww) base += s_wcnt[ww];
                __syncthreads();
            }
        }
        __syncthreads();
    }

    const int nsupT = (K < NDET) ? (V - K) : 0;

    // ---- output: boxes | scores | labels | valid (class-major) ----
    float* out_boxes  = out;
    float* out_scores = out + NFG * NDET * 4;
    float* out_labels = out + NFG * NDET * 4 + NFG * NDET;
    float* out_valid  = out + NFG * NDET * 4 + 2 * NFG * NDET;
    const int base_o = cc * NDET;

    for (int k = tid; k < NDET; k += NBLK) {
        int n; float sc, vf;
        if (k < K) {
            n = s_ord[s_keepOut[k]];
            sc = s_scu[n]; vf = 1.0f;
        } else {
            int j = k - K;
            n = (j < nsupT) ? s_ord[s_supOut[j]] : s_invOut[j - nsupT];
            sc = -1.0f; vf = 0.0f;
        }
        out_boxes[(base_o + k) * 4 + 0] = s_x1u[n];
        out_boxes[(base_o + k) * 4 + 1] = s_y1u[n];
        out_boxes[(base_o + k) * 4 + 2] = s_x2u[n];
        out_boxes[(base_o + k) * 4 + 3] = s_y2u[n];
        out_scores[base_o + k] = sc;
        out_labels[base_o + k] = (float)(cc + 1);
        out_valid[base_o + k]  = vf;
    }
}

extern "C" void kernel_launch(void* const* d_in, const int* in_sizes, int n_in,
                              void* d_out, int out_size, void* d_ws, size_t ws_size,
                              hipStream_t stream) {
    const float* logits = (const float*)d_in[0];  // [2000, 81]
    const float* reg    = (const float*)d_in[1];  // [2000, 324]
    const float* prop   = (const float*)d_in[2];  // [2000, 4]
    float*  out    = (float*)d_out;
    float*  scoreV = (float*)d_ws;                       // 80*2000 floats = 640 KB
    float4* boxT   = (float4*)(scoreV + NFG * NPROP);    // 80*2000 float4 = 2.56 MB

    prep_kernel<<<NPROP / R, PBLK, 0, stream>>>(logits, reg, prop, scoreV, boxT);
    perclass_kernel<<<NFG, NBLK, 0, stream>>>(scoreV, boxT, out);
}